// Round 1
// baseline (4557.085 us; speedup 1.0000x reference)
//
#include <hip/hip_runtime.h>
#include <math.h>

#define B_ 8
#define T_ 4096
#define H_ 1024
#define K_ 128
#define V_ 128
#define OUT_ 1024
#define NPROJ 512
#define M_ (B_*T_)          // 32768

// ---------------- Kernel 1: proj GEMM  qkgv = hidden @ W_proj + b_proj, sigmoid on k,g cols
#define PBM 128
#define PBN 64
#define PBK 16

__global__ __launch_bounds__(256)
void proj_gemm(const float* __restrict__ A, const float* __restrict__ W,
               const float* __restrict__ bias, float* __restrict__ Cq) {
  __shared__ float As[PBK][PBM+4];
  __shared__ float Bs[PBK][PBN];
  int tid = threadIdx.x;
  int tx = tid & 15, ty = tid >> 4;
  long row0 = (long)blockIdx.y * PBM;
  int col0 = blockIdx.x * PBN;
  float acc[8][4];
  #pragma unroll
  for (int i=0;i<8;i++)
    #pragma unroll
    for (int j=0;j<4;j++) acc[i][j]=0.f;

  for (int k0 = 0; k0 < H_; k0 += PBK) {
    #pragma unroll
    for (int r = 0; r < 2; ++r) {
      int idx = tid + r*256;            // 0..511 -> 512 float4 = 128x16 tile
      int row = idx >> 2;
      int lk = (idx & 3) << 2;
      float4 a4 = *(const float4*)(A + (row0 + row)*H_ + k0 + lk);
      As[lk+0][row] = a4.x; As[lk+1][row] = a4.y;
      As[lk+2][row] = a4.z; As[lk+3][row] = a4.w;
    }
    {
      int lkB = tid >> 4;               // 0..15
      int ln = (tid & 15) << 2;
      *(float4*)&Bs[lkB][ln] = *(const float4*)(W + (long)(k0+lkB)*NPROJ + col0 + ln);
    }
    __syncthreads();
    #pragma unroll
    for (int kk = 0; kk < PBK; ++kk) {
      float4 av0 = *(const float4*)&As[kk][ty*8];
      float4 av1 = *(const float4*)&As[kk][ty*8+4];
      float4 bv  = *(const float4*)&Bs[kk][tx*4];
      float a0[8] = {av0.x,av0.y,av0.z,av0.w,av1.x,av1.y,av1.z,av1.w};
      float b0[4] = {bv.x,bv.y,bv.z,bv.w};
      #pragma unroll
      for (int i=0;i<8;i++)
        #pragma unroll
        for (int j=0;j<4;j++)
          acc[i][j] = fmaf(a0[i], b0[j], acc[i][j]);
    }
    __syncthreads();
  }
  #pragma unroll
  for (int i=0;i<8;i++) {
    long row = row0 + ty*8 + i;
    float vals[4];
    #pragma unroll
    for (int j=0;j<4;j++) {
      int col = col0 + tx*4 + j;
      float v = acc[i][j] + bias[col];
      if (col >= K_ && col < 3*K_) v = 1.f/(1.f + __expf(-v));  // sigmoid on k,g
      vals[j] = v;
    }
    *(float4*)(Cq + row*NPROJ + col0 + tx*4) = make_float4(vals[0],vals[1],vals[2],vals[3]);
  }
}

// ---------------- Kernel 2: sequential scan, parallel over (b, k-block, v-block)
// wg = 64 threads; lane -> (kg = lane>>4 owns 8 k's, v_l = lane&15 owns 1 v)
// cell slice 32k x 16v in regs (8 per thread). o partial per k-block written to opart.
#define CS 64

__global__ __launch_bounds__(64)
void scan_kernel(const float* __restrict__ qkgv, float* __restrict__ opart,
                 float* __restrict__ fstate) {
  __shared__ float qs[CS][32], ks[CS][32], gs[CS][32], vs[CS][16];
  int lane = threadIdx.x;
  int vblk = blockIdx.x;    // 0..7
  int kblk = blockIdx.y;    // 0..3
  int b    = blockIdx.z;    // 0..7
  int v_l = lane & 15;
  int kg  = lane >> 4;      // 0..3
  int kbase = kblk*32 + kg*8;
  int vcol = vblk*16 + v_l;
  float cell[8];
  #pragma unroll
  for (int j=0;j<8;j++) cell[j]=0.f;

  const float* src_b = qkgv + (long)b * T_ * NPROJ;
  long obase = ((long)kblk * M_ + (long)b * T_) * V_ + vblk*16;

  for (int t0 = 0; t0 < T_; t0 += CS) {
    __syncthreads();
    for (int i = lane; i < CS*112; i += 64) {
      int tt = i / 112;
      int cc = i - tt*112;
      const float* src = src_b + (long)(t0 + tt) * NPROJ;
      if (cc < 96) {
        int part = cc >> 5;        // 0=q 1=k 2=g
        int kk = cc & 31;
        float val = src[part*128 + kblk*32 + kk];
        if (part == 0) qs[tt][kk] = val;
        else if (part == 1) ks[tt][kk] = val;
        else gs[tt][kk] = val;
      } else {
        vs[tt][cc-96] = src[384 + vblk*16 + (cc-96)];
      }
    }
    __syncthreads();
    #pragma unroll 2
    for (int t2 = 0; t2 < CS; ++t2) {
      float vv = vs[t2][v_l];
      float4 k0 = *(const float4*)&ks[t2][kg*8];
      float4 k1 = *(const float4*)&ks[t2][kg*8+4];
      float4 g0 = *(const float4*)&gs[t2][kg*8];
      float4 g1 = *(const float4*)&gs[t2][kg*8+4];
      float4 q0 = *(const float4*)&qs[t2][kg*8];
      float4 q1 = *(const float4*)&qs[t2][kg*8+4];
      cell[0] = fmaf(cell[0], g0.x, k0.x*vv);
      cell[1] = fmaf(cell[1], g0.y, k0.y*vv);
      cell[2] = fmaf(cell[2], g0.z, k0.z*vv);
      cell[3] = fmaf(cell[3], g0.w, k0.w*vv);
      cell[4] = fmaf(cell[4], g1.x, k1.x*vv);
      cell[5] = fmaf(cell[5], g1.y, k1.y*vv);
      cell[6] = fmaf(cell[6], g1.z, k1.z*vv);
      cell[7] = fmaf(cell[7], g1.w, k1.w*vv);
      float os;
      os = q0.x*cell[0];
      os = fmaf(q0.y, cell[1], os);
      os = fmaf(q0.z, cell[2], os);
      os = fmaf(q0.w, cell[3], os);
      os = fmaf(q1.x, cell[4], os);
      os = fmaf(q1.y, cell[5], os);
      os = fmaf(q1.z, cell[6], os);
      os = fmaf(q1.w, cell[7], os);
      os += __shfl_xor(os, 16);
      os += __shfl_xor(os, 32);
      if (kg == 0) {
        opart[obase + (long)(t0+t2)*V_ + v_l] = os;
      }
    }
  }
  // final state (b, k, v)
  #pragma unroll
  for (int j=0;j<8;j++) {
    fstate[((long)b*K_ + kbase + j)*V_ + vcol] = cell[j];
  }
}

// ---------------- Kernel 3: sum the 4 k-block partials into opart[kblk=0] (in place)
__global__ __launch_bounds__(256)
void reduce_opart(float* __restrict__ opart) {
  long i4 = (long)blockIdx.x*256 + threadIdx.x;   // M_*V_/4 = 1048576 float4's
  float4* p = (float4*)opart;
  const long stride = (long)M_*V_/4;              // one k-block in float4
  float4 a = p[i4];
  float4 b = p[i4 + stride];
  float4 c = p[i4 + 2*stride];
  float4 d = p[i4 + 3*stride];
  a.x += b.x + c.x + d.x;
  a.y += b.y + c.y + d.y;
  a.z += b.z + c.z + d.z;
  a.w += b.w + c.w + d.w;
  p[i4] = a;
}

// ---------------- Kernel 4: out GEMM  outputs = o @ W_out + b_out
#define OBM 128
#define OBN 64
#define OBK 16

__global__ __launch_bounds__(256)
void out_gemm(const float* __restrict__ A, const float* __restrict__ W,
              const float* __restrict__ bias, float* __restrict__ Cout) {
  __shared__ float As[OBK][OBM+4];
  __shared__ float Bs[OBK][OBN];
  int tid = threadIdx.x;
  int tx = tid & 15, ty = tid >> 4;
  long row0 = (long)blockIdx.y * OBM;
  int col0 = blockIdx.x * OBN;
  float acc[8][4];
  #pragma unroll
  for (int i=0;i<8;i++)
    #pragma unroll
    for (int j=0;j<4;j++) acc[i][j]=0.f;

  for (int k0 = 0; k0 < V_; k0 += OBK) {
    #pragma unroll
    for (int r = 0; r < 2; ++r) {
      int idx = tid + r*256;
      int row = idx >> 2;
      int lk = (idx & 3) << 2;
      float4 a4 = *(const float4*)(A + (row0 + row)*V_ + k0 + lk);
      As[lk+0][row] = a4.x; As[lk+1][row] = a4.y;
      As[lk+2][row] = a4.z; As[lk+3][row] = a4.w;
    }
    {
      int lkB = tid >> 4;
      int ln = (tid & 15) << 2;
      *(float4*)&Bs[lkB][ln] = *(const float4*)(W + (long)(k0+lkB)*OUT_ + col0 + ln);
    }
    __syncthreads();
    #pragma unroll
    for (int kk = 0; kk < OBK; ++kk) {
      float4 av0 = *(const float4*)&As[kk][ty*8];
      float4 av1 = *(const float4*)&As[kk][ty*8+4];
      float4 bv  = *(const float4*)&Bs[kk][tx*4];
      float a0[8] = {av0.x,av0.y,av0.z,av0.w,av1.x,av1.y,av1.z,av1.w};
      float b0[4] = {bv.x,bv.y,bv.z,bv.w};
      #pragma unroll
      for (int i=0;i<8;i++)
        #pragma unroll
        for (int j=0;j<4;j++)
          acc[i][j] = fmaf(a0[i], b0[j], acc[i][j]);
    }
    __syncthreads();
  }
  #pragma unroll
  for (int i=0;i<8;i++) {
    long row = row0 + ty*8 + i;
    float vals[4];
    #pragma unroll
    for (int j=0;j<4;j++) {
      int col = col0 + tx*4 + j;
      vals[j] = acc[i][j] + bias[col];
    }
    *(float4*)(Cout + row*OUT_ + col0 + tx*4) = make_float4(vals[0],vals[1],vals[2],vals[3]);
  }
}

extern "C" void kernel_launch(void* const* d_in, const int* in_sizes, int n_in,
                              void* d_out, int out_size, void* d_ws, size_t ws_size,
                              hipStream_t stream) {
  const float* hidden = (const float*)d_in[0];   // (B,T,H)
  const float* Wp     = (const float*)d_in[1];   // (H,512)
  const float* bp     = (const float*)d_in[2];   // (512)
  const float* Wo     = (const float*)d_in[3];   // (128,1024)
  const float* bo     = (const float*)d_in[4];   // (1024)
  float* out    = (float*)d_out;                 // outputs (B,T,1024) then final_state (B,128,128)
  float* fstate = out + (long)M_ * OUT_;
  float* ws     = (float*)d_ws;
  float* qkgv   = ws;                            // M_*512 floats = 64 MB
  float* opart  = ws + (long)M_ * NPROJ;         // 4 * M_*128 floats = 64 MB

  proj_gemm<<<dim3(NPROJ/PBN, M_/PBM), 256, 0, stream>>>(hidden, Wp, bp, qkgv);
  scan_kernel<<<dim3(8, 4, 8), 64, 0, stream>>>(qkgv, opart, fstate);
  reduce_opart<<<4096, 256, 0, stream>>>(opart);
  out_gemm<<<dim3(OUT_/OBN, M_/OBM), 256, 0, stream>>>(opart, Wo, bo, out);
}

// Round 2
// 1151.012 us; speedup vs baseline: 3.9592x; 3.9592x over previous
//
#include <hip/hip_runtime.h>
#include <math.h>

#define B_ 8
#define T_ 4096
#define H_ 1024
#define K_ 128
#define V_ 128
#define OUT_ 1024
#define NPROJ 512
#define M_ (B_*T_)          // 32768

// ---------------- Kernel 1: proj GEMM  qkgv = hidden @ W_proj + b_proj, sigmoid on k,g cols
#define PBM 128
#define PBN 64
#define PBK 16

__global__ __launch_bounds__(256)
void proj_gemm(const float* __restrict__ A, const float* __restrict__ W,
               const float* __restrict__ bias, float* __restrict__ Cq) {
  __shared__ float As[PBK][PBM+4];
  __shared__ float Bs[PBK][PBN];
  int tid = threadIdx.x;
  int tx = tid & 15, ty = tid >> 4;
  long row0 = (long)blockIdx.y * PBM;
  int col0 = blockIdx.x * PBN;
  float acc[8][4];
  #pragma unroll
  for (int i=0;i<8;i++)
    #pragma unroll
    for (int j=0;j<4;j++) acc[i][j]=0.f;

  for (int k0 = 0; k0 < H_; k0 += PBK) {
    #pragma unroll
    for (int r = 0; r < 2; ++r) {
      int idx = tid + r*256;            // 0..511 -> 512 float4 = 128x16 tile
      int row = idx >> 2;
      int lk = (idx & 3) << 2;
      float4 a4 = *(const float4*)(A + (row0 + row)*H_ + k0 + lk);
      As[lk+0][row] = a4.x; As[lk+1][row] = a4.y;
      As[lk+2][row] = a4.z; As[lk+3][row] = a4.w;
    }
    {
      int lkB = tid >> 4;               // 0..15
      int ln = (tid & 15) << 2;
      *(float4*)&Bs[lkB][ln] = *(const float4*)(W + (long)(k0+lkB)*NPROJ + col0 + ln);
    }
    __syncthreads();
    #pragma unroll
    for (int kk = 0; kk < PBK; ++kk) {
      float4 av0 = *(const float4*)&As[kk][ty*8];
      float4 av1 = *(const float4*)&As[kk][ty*8+4];
      float4 bv  = *(const float4*)&Bs[kk][tx*4];
      float a0[8] = {av0.x,av0.y,av0.z,av0.w,av1.x,av1.y,av1.z,av1.w};
      float b0[4] = {bv.x,bv.y,bv.z,bv.w};
      #pragma unroll
      for (int i=0;i<8;i++)
        #pragma unroll
        for (int j=0;j<4;j++)
          acc[i][j] = fmaf(a0[i], b0[j], acc[i][j]);
    }
    __syncthreads();
  }
  #pragma unroll
  for (int i=0;i<8;i++) {
    long row = row0 + ty*8 + i;
    float vals[4];
    #pragma unroll
    for (int j=0;j<4;j++) {
      int col = col0 + tx*4 + j;
      float v = acc[i][j] + bias[col];
      if (col >= K_ && col < 3*K_) v = 1.f/(1.f + __expf(-v));  // sigmoid on k,g
      vals[j] = v;
    }
    *(float4*)(Cq + row*NPROJ + col0 + tx*4) = make_float4(vals[0],vals[1],vals[2],vals[3]);
  }
}

// ---------------- Kernel 2: sequential scan v2
// grid (vb 8, kb 4, b 8) = 256 blocks x 1 wave. Per block: 32 k's x 16 v's.
// lane: kg = lane>>4 (4 groups x 8 k), v_l = lane&15. cell[8] in regs.
// Register-staged double-buffered chunk loads (CS2=32), LDS-deferred k-group
// reduce (osum), no barriers (single wave).
#define CS2 32

__global__ __launch_bounds__(64)
void scan_kernel2(const float* __restrict__ qkgv, float* __restrict__ opart,
                  float* __restrict__ fstate) {
  __shared__ float qs[CS2][32], ks[CS2][32], gs[CS2][32], vsm[CS2][16];
  __shared__ float osum[CS2][64];
  int lane = threadIdx.x;
  int vb = blockIdx.x;    // 0..7
  int kb = blockIdx.y;    // 0..3
  int b  = blockIdx.z;    // 0..7
  int v_l = lane & 15;
  int kg  = lane >> 4;
  const float* src_b = qkgv + (long)b * T_ * NPROJ;
  long obase = ((long)kb * M_ + (long)b * T_) * V_ + vb*16;

  float cell[8];
  #pragma unroll
  for (int j=0;j<8;j++) cell[j]=0.f;

  float4 rq[4], rk[4], rg[4], rv[2];

  // load one chunk's q/k/g/v slices into registers (coalesced float4)
  #define LOAD_CHUNK(t0_) do { \
    _Pragma("unroll") \
    for (int j=0;j<4;j++){ \
      int idx = j*64 + lane; \
      int tt = idx >> 3; int c4 = (idx & 7) << 2; \
      const float* row = src_b + (long)((t0_)+tt)*NPROJ + kb*32 + c4; \
      rq[j] = *(const float4*)(row); \
      rk[j] = *(const float4*)(row + 128); \
      rg[j] = *(const float4*)(row + 256); \
    } \
    _Pragma("unroll") \
    for (int j=0;j<2;j++){ \
      int idx = j*64 + lane; \
      int tt = idx >> 2; int c4 = (idx & 3) << 2; \
      rv[j] = *(const float4*)(src_b + (long)((t0_)+tt)*NPROJ + 384 + vb*16 + c4); \
    } \
  } while(0)

  LOAD_CHUNK(0);

  for (int t0 = 0; t0 < T_; t0 += CS2) {
    // commit staged regs to LDS
    #pragma unroll
    for (int j=0;j<4;j++){
      int idx = j*64 + lane;
      int tt = idx >> 3; int c4 = (idx & 7) << 2;
      *(float4*)&qs[tt][c4] = rq[j];
      *(float4*)&ks[tt][c4] = rk[j];
      *(float4*)&gs[tt][c4] = rg[j];
    }
    #pragma unroll
    for (int j=0;j<2;j++){
      int idx = j*64 + lane;
      *(float4*)&vsm[idx>>2][(idx&3)<<2] = rv[j];
    }
    // prefetch next chunk into regs (HBM latency hides under compute below)
    if (t0 + CS2 < T_) { LOAD_CHUNK(t0 + CS2); }

    // compute 32 timesteps
    #pragma unroll 4
    for (int t=0;t<CS2;++t){
      float vv = vsm[t][v_l];
      float4 k0 = *(const float4*)&ks[t][kg*8];
      float4 k1 = *(const float4*)&ks[t][kg*8+4];
      float4 g0 = *(const float4*)&gs[t][kg*8];
      float4 g1 = *(const float4*)&gs[t][kg*8+4];
      float4 q0 = *(const float4*)&qs[t][kg*8];
      float4 q1 = *(const float4*)&qs[t][kg*8+4];
      cell[0] = fmaf(cell[0], g0.x, k0.x*vv);
      cell[1] = fmaf(cell[1], g0.y, k0.y*vv);
      cell[2] = fmaf(cell[2], g0.z, k0.z*vv);
      cell[3] = fmaf(cell[3], g0.w, k0.w*vv);
      cell[4] = fmaf(cell[4], g1.x, k1.x*vv);
      cell[5] = fmaf(cell[5], g1.y, k1.y*vv);
      cell[6] = fmaf(cell[6], g1.z, k1.z*vv);
      cell[7] = fmaf(cell[7], g1.w, k1.w*vv);
      // readout partial over this lane's 8 k's (tree, short dep chains)
      float p01 = fmaf(q0.y, cell[1], q0.x*cell[0]);
      float p23 = fmaf(q0.w, cell[3], q0.z*cell[2]);
      float p45 = fmaf(q1.y, cell[5], q1.x*cell[4]);
      float p67 = fmaf(q1.w, cell[7], q1.z*cell[6]);
      osum[t][lane] = (p01 + p23) + (p45 + p67);   // ds_write, off critical path
    }

    // per-chunk reduce over the 4 k-groups + coalesced store
    #pragma unroll
    for (int j=0;j<8;j++){
      int idx = j*64 + lane;
      int tt = idx >> 4; int v = idx & 15;
      float s = (osum[tt][v] + osum[tt][16+v]) + (osum[tt][32+v] + osum[tt][48+v]);
      opart[obase + (long)(t0+tt)*V_ + v] = s;
    }
  }

  // final state (b, k, v)
  int kbase = kb*32 + kg*8;
  int vcol = vb*16 + v_l;
  #pragma unroll
  for (int j=0;j<8;j++) {
    fstate[((long)b*K_ + kbase + j)*V_ + vcol] = cell[j];
  }
  #undef LOAD_CHUNK
}

// ---------------- Kernel 3: sum the 4 k-block partials into opart[kblk=0] (in place)
__global__ __launch_bounds__(256)
void reduce_opart(float* __restrict__ opart) {
  long i4 = (long)blockIdx.x*256 + threadIdx.x;   // M_*V_/4 = 1048576 float4's
  float4* p = (float4*)opart;
  const long stride = (long)M_*V_/4;              // one k-block in float4
  float4 a = p[i4];
  float4 b = p[i4 + stride];
  float4 c = p[i4 + 2*stride];
  float4 d = p[i4 + 3*stride];
  a.x += b.x + c.x + d.x;
  a.y += b.y + c.y + d.y;
  a.z += b.z + c.z + d.z;
  a.w += b.w + c.w + d.w;
  p[i4] = a;
}

// ---------------- Kernel 4: out GEMM  outputs = o @ W_out + b_out
#define OBM 128
#define OBN 64
#define OBK 16

__global__ __launch_bounds__(256)
void out_gemm(const float* __restrict__ A, const float* __restrict__ W,
              const float* __restrict__ bias, float* __restrict__ Cout) {
  __shared__ float As[OBK][OBM+4];
  __shared__ float Bs[OBK][OBN];
  int tid = threadIdx.x;
  int tx = tid & 15, ty = tid >> 4;
  long row0 = (long)blockIdx.y * OBM;
  int col0 = blockIdx.x * OBN;
  float acc[8][4];
  #pragma unroll
  for (int i=0;i<8;i++)
    #pragma unroll
    for (int j=0;j<4;j++) acc[i][j]=0.f;

  for (int k0 = 0; k0 < V_; k0 += OBK) {
    #pragma unroll
    for (int r = 0; r < 2; ++r) {
      int idx = tid + r*256;
      int row = idx >> 2;
      int lk = (idx & 3) << 2;
      float4 a4 = *(const float4*)(A + (row0 + row)*V_ + k0 + lk);
      As[lk+0][row] = a4.x; As[lk+1][row] = a4.y;
      As[lk+2][row] = a4.z; As[lk+3][row] = a4.w;
    }
    {
      int lkB = tid >> 4;
      int ln = (tid & 15) << 2;
      *(float4*)&Bs[lkB][ln] = *(const float4*)(W + (long)(k0+lkB)*OUT_ + col0 + ln);
    }
    __syncthreads();
    #pragma unroll
    for (int kk = 0; kk < OBK; ++kk) {
      float4 av0 = *(const float4*)&As[kk][ty*8];
      float4 av1 = *(const float4*)&As[kk][ty*8+4];
      float4 bv  = *(const float4*)&Bs[kk][tx*4];
      float a0[8] = {av0.x,av0.y,av0.z,av0.w,av1.x,av1.y,av1.z,av1.w};
      float b0[4] = {bv.x,bv.y,bv.z,bv.w};
      #pragma unroll
      for (int i=0;i<8;i++)
        #pragma unroll
        for (int j=0;j<4;j++)
          acc[i][j] = fmaf(a0[i], b0[j], acc[i][j]);
    }
    __syncthreads();
  }
  #pragma unroll
  for (int i=0;i<8;i++) {
    long row = row0 + ty*8 + i;
    float vals[4];
    #pragma unroll
    for (int j=0;j<4;j++) {
      int col = col0 + tx*4 + j;
      vals[j] = acc[i][j] + bias[col];
    }
    *(float4*)(Cout + row*OUT_ + col0 + tx*4) = make_float4(vals[0],vals[1],vals[2],vals[3]);
  }
}

extern "C" void kernel_launch(void* const* d_in, const int* in_sizes, int n_in,
                              void* d_out, int out_size, void* d_ws, size_t ws_size,
                              hipStream_t stream) {
  const float* hidden = (const float*)d_in[0];   // (B,T,H)
  const float* Wp     = (const float*)d_in[1];   // (H,512)
  const float* bp     = (const float*)d_in[2];   // (512)
  const float* Wo     = (const float*)d_in[3];   // (128,1024)
  const float* bo     = (const float*)d_in[4];   // (1024)
  float* out    = (float*)d_out;                 // outputs (B,T,1024) then final_state (B,128,128)
  float* fstate = out + (long)M_ * OUT_;
  float* ws     = (float*)d_ws;
  float* qkgv   = ws;                            // M_*512 floats = 64 MB
  float* opart  = ws + (long)M_ * NPROJ;         // 4 * M_*128 floats = 64 MB

  proj_gemm<<<dim3(NPROJ/PBN, M_/PBM), 256, 0, stream>>>(hidden, Wp, bp, qkgv);
  scan_kernel2<<<dim3(8, 4, 8), 64, 0, stream>>>(qkgv, opart, fstate);
  reduce_opart<<<4096, 256, 0, stream>>>(opart);
  out_gemm<<<dim3(OUT_/OBN, M_/OBM), 256, 0, stream>>>(opart, Wo, bo, out);
}

// Round 3
// 441.868 us; speedup vs baseline: 10.3132x; 2.6049x over previous
//
#include <hip/hip_runtime.h>
#include <math.h>

#define B_ 8
#define T_ 4096
#define H_ 1024
#define K_ 128
#define V_ 128
#define OUT_ 1024
#define NPROJ 512
#define M_ (B_*T_)          // 32768

typedef __attribute__((ext_vector_type(8))) short bf16x8;
typedef __attribute__((ext_vector_type(4))) float f32x4;

__device__ inline unsigned short f2bf(float f){
  union{float f; unsigned int u;} x; x.f = f;
  unsigned int r = x.u + 0x7fff + ((x.u>>16)&1);   // RNE
  return (unsigned short)(r>>16);
}
__device__ inline float bf2f(unsigned short u){
  union{unsigned int i; float f;} x; x.i = ((unsigned int)u)<<16; return x.f;
}

#define GL16(gp, lp) __builtin_amdgcn_global_load_lds(\
  (const __attribute__((address_space(1))) unsigned int*)(gp), \
  (__attribute__((address_space(3))) unsigned int*)(lp), 16, 0, 0)

// ---------------- convert hidden f32 -> bf16
__global__ __launch_bounds__(256)
void convH(const float* __restrict__ x, unsigned short* __restrict__ y) {
  long i = (long)blockIdx.x*256 + threadIdx.x;   // n/8 threads
  float4 a = *(const float4*)(x + i*8);
  float4 b = *(const float4*)(x + i*8 + 4);
  unsigned short o[8] = {f2bf(a.x),f2bf(a.y),f2bf(a.z),f2bf(a.w),
                         f2bf(b.x),f2bf(b.y),f2bf(b.z),f2bf(b.w)};
  *(uint4*)(y + i*8) = *(uint4*)o;
}

// ---------------- transpose+convert weights: Wpt[n][k]=Wp[k][n], Wot[o][v]=Wo[v][o]
__global__ __launch_bounds__(256)
void convW(const float* __restrict__ Wp, const float* __restrict__ Wo,
           unsigned short* __restrict__ Wpt, unsigned short* __restrict__ Wot) {
  int i = blockIdx.x*256 + threadIdx.x;
  if (i < 512*1024) {
    int n = i >> 10, k = i & 1023;
    Wpt[i] = f2bf(Wp[(long)k*512 + n]);
  } else {
    int j = i - 512*1024;             // < 1024*128
    int o = j >> 7, v = j & 127;
    Wot[j] = f2bf(Wo[(long)v*1024 + o]);
  }
}

// ---------------- proj MFMA GEMM: [32768x1024]bf16 @ [1024x512] -> q/k/g/v arrays
// grid (4 colblocks, 256 rowblocks), 256 thr. BM=BN=128, BK=32.
__global__ __launch_bounds__(256)
void proj_mfma(const unsigned short* __restrict__ A, const unsigned short* __restrict__ Bt,
               const float* __restrict__ bias,
               unsigned short* __restrict__ qbf, unsigned short* __restrict__ kbf,
               float* __restrict__ gf, unsigned short* __restrict__ vbf) {
  __shared__ unsigned short As[128*32];
  __shared__ unsigned short Bs[128*32];
  int tid = threadIdx.x, lane = tid & 63, wid = tid >> 6;
  long row0 = (long)blockIdx.y * 128;
  int bx = blockIdx.x;
  int col0 = bx * 128;
  f32x4 acc[4][4];
  #pragma unroll
  for (int i=0;i<4;i++)
    #pragma unroll
    for (int j=0;j<4;j++) acc[i][j] = (f32x4){0.f,0.f,0.f,0.f};

  const unsigned short* Ab = A + row0*1024;
  const unsigned short* Bb = Bt + (long)col0*1024;
  int srow = lane >> 2;          // 0..15
  int soff = (lane & 3) * 8;     // element offset within 32-elem row
  int wrow = (wid>>1)*64, wcol = (wid&1)*64;

  for (int k0 = 0; k0 < 1024; k0 += 32) {
    #pragma unroll
    for (int i=0;i<2;i++){
      int r = wid*32 + i*16;
      GL16(Ab + (long)(r + srow)*1024 + k0 + soff, &As[r*32]);
      GL16(Bb + (long)(r + srow)*1024 + k0 + soff, &Bs[r*32]);
    }
    __syncthreads();
    bf16x8 af[4], bfr[4];
    #pragma unroll
    for (int mi=0;mi<4;mi++)
      af[mi] = *(const bf16x8*)&As[(wrow + mi*16 + (lane&15))*32 + (lane>>4)*8];
    #pragma unroll
    for (int ni=0;ni<4;ni++)
      bfr[ni] = *(const bf16x8*)&Bs[(wcol + ni*16 + (lane&15))*32 + (lane>>4)*8];
    #pragma unroll
    for (int mi=0;mi<4;mi++)
      #pragma unroll
      for (int ni=0;ni<4;ni++)
        acc[mi][ni] = __builtin_amdgcn_mfma_f32_16x16x32_bf16(af[mi], bfr[ni], acc[mi][ni], 0,0,0);
    __syncthreads();
  }

  #pragma unroll
  for (int mi=0;mi<4;mi++){
    #pragma unroll
    for (int ni=0;ni<4;ni++){
      int cloc = wcol + ni*16 + (lane&15);
      float bsv = bias[col0 + cloc];
      #pragma unroll
      for (int r=0;r<4;r++){
        long grow = row0 + wrow + mi*16 + (lane>>4)*4 + r;
        float v = acc[mi][ni][r] + bsv;
        long off = grow*128 + cloc;
        if (bx == 0)      qbf[off] = f2bf(v);
        else if (bx == 1) kbf[off] = f2bf(1.f/(1.f+__expf(-v)));
        else if (bx == 2) gf[off]  = 1.f/(1.f+__expf(-v));
        else              vbf[off] = f2bf(v);
      }
    }
  }
}

// ---------------- scan v3: grid (vb 8, kb 8, b 8) = 512 blocks x 1 wave.
// Per block: 16 k x 16 v; lane: kg=lane>>4 owns 4 k's, v_l=lane&15 owns 1 v.
#define CS3 32
#define LP 20   // padded LDS row (floats), 16B-aligned stride

__global__ __launch_bounds__(64)
void scan3(const unsigned short* __restrict__ qb, const unsigned short* __restrict__ kbp,
           const unsigned short* __restrict__ vbp, const float* __restrict__ gfp,
           unsigned short* __restrict__ opart, float* __restrict__ fstate) {
  __shared__ float qs[CS3][LP], ks[CS3][LP], vs[CS3][LP], gs[CS3][LP];
  __shared__ float osum[CS3][64];
  int lane = threadIdx.x;
  int vbk = blockIdx.x, kbk = blockIdx.y, b = blockIdx.z;
  int v_l = lane & 15;
  int kg  = lane >> 4;
  long tb = (long)b * T_;
  const unsigned short* qsrc = qb  + tb*128 + kbk*16;
  const unsigned short* ksrc = kbp + tb*128 + kbk*16;
  const unsigned short* vsrc = vbp + tb*128 + vbk*16;
  const float* gsrc = gfp + tb*128 + kbk*16;
  long obase = ((long)kbk * M_ + tb) * V_ + vbk*16;

  float cell[4] = {0.f,0.f,0.f,0.f};
  uint4 rq, rk, rv; float4 rg0, rg1;
  int tt2 = lane >> 1, h8 = (lane & 1) * 8;
  int tg = lane >> 2, c4 = (lane & 3) * 4;

  #define LOADC(t0_) do { \
    rq = *(const uint4*)(qsrc + ((long)(t0_)+tt2)*128 + h8); \
    rk = *(const uint4*)(ksrc + ((long)(t0_)+tt2)*128 + h8); \
    rv = *(const uint4*)(vsrc + ((long)(t0_)+tt2)*128 + h8); \
    rg0 = *(const float4*)(gsrc + ((long)(t0_)+tg)*128 + c4); \
    rg1 = *(const float4*)(gsrc + ((long)(t0_)+16+tg)*128 + c4); \
  } while(0)

  LOADC(0);

  for (int t0 = 0; t0 < T_; t0 += CS3) {
    // commit staged regs to LDS (bf16 -> f32 once per element)
    {
      unsigned int* pq = (unsigned int*)&rq;
      unsigned int* pk = (unsigned int*)&rk;
      unsigned int* pv = (unsigned int*)&rv;
      #pragma unroll
      for (int j=0;j<4;j++){
        *(float2*)&qs[tt2][h8+j*2] = make_float2(bf2f(pq[j]&0xffff), bf2f(pq[j]>>16));
        *(float2*)&ks[tt2][h8+j*2] = make_float2(bf2f(pk[j]&0xffff), bf2f(pk[j]>>16));
        *(float2*)&vs[tt2][h8+j*2] = make_float2(bf2f(pv[j]&0xffff), bf2f(pv[j]>>16));
      }
      *(float4*)&gs[tg][c4]    = rg0;
      *(float4*)&gs[16+tg][c4] = rg1;
    }
    if (t0 + CS3 < T_) { LOADC(t0 + CS3); }

    #pragma unroll 4
    for (int t=0;t<CS3;++t){
      float vv = vs[t][v_l];
      float4 k4 = *(const float4*)&ks[t][kg*4];
      float4 g4 = *(const float4*)&gs[t][kg*4];
      float4 q4 = *(const float4*)&qs[t][kg*4];
      cell[0] = fmaf(cell[0], g4.x, k4.x*vv);
      cell[1] = fmaf(cell[1], g4.y, k4.y*vv);
      cell[2] = fmaf(cell[2], g4.z, k4.z*vv);
      cell[3] = fmaf(cell[3], g4.w, k4.w*vv);
      float p01 = fmaf(q4.y, cell[1], q4.x*cell[0]);
      float p23 = fmaf(q4.w, cell[3], q4.z*cell[2]);
      osum[t][lane] = p01 + p23;
    }

    #pragma unroll
    for (int j=0;j<8;j++){
      int idx = j*64 + lane;
      int tt = idx >> 4, v = idx & 15;
      float s = (osum[tt][v] + osum[tt][16+v]) + (osum[tt][32+v] + osum[tt][48+v]);
      opart[obase + (long)(t0+tt)*V_ + v] = f2bf(s);
    }
  }

  int kbase = kbk*16 + kg*4;
  #pragma unroll
  for (int j=0;j<4;j++)
    fstate[((long)b*K_ + kbase + j)*V_ + vbk*16 + v_l] = cell[j];
  #undef LOADC
}

// ---------------- reduce 8 bf16 partials -> o bf16
__global__ __launch_bounds__(256)
void reduce8(const unsigned short* __restrict__ opart, unsigned short* __restrict__ obf) {
  long i = ((long)blockIdx.x*256 + threadIdx.x) * 8;   // over M*V
  const long S = (long)M_*V_;
  float s[8] = {0,0,0,0,0,0,0,0};
  #pragma unroll
  for (int p=0;p<8;p++){
    uint4 u = *(const uint4*)(opart + p*S + i);
    unsigned int* w = (unsigned int*)&u;
    #pragma unroll
    for (int j=0;j<4;j++){
      s[2*j]   += bf2f(w[j] & 0xffff);
      s[2*j+1] += bf2f(w[j] >> 16);
    }
  }
  unsigned short o[8];
  #pragma unroll
  for (int j=0;j<8;j++) o[j] = f2bf(s[j]);
  *(uint4*)(obf + i) = *(uint4*)o;
}

// ---------------- out MFMA GEMM: [32768x128]bf16 @ [128x1024] + bias -> f32
__global__ __launch_bounds__(256)
void out_mfma(const unsigned short* __restrict__ A, const unsigned short* __restrict__ Bt,
              const float* __restrict__ bias, float* __restrict__ C) {
  __shared__ unsigned short As[128*32];
  __shared__ unsigned short Bs[128*32];
  int tid = threadIdx.x, lane = tid & 63, wid = tid >> 6;
  long row0 = (long)blockIdx.y * 128;
  int col0 = blockIdx.x * 128;
  f32x4 acc[4][4];
  #pragma unroll
  for (int i=0;i<4;i++)
    #pragma unroll
    for (int j=0;j<4;j++) acc[i][j] = (f32x4){0.f,0.f,0.f,0.f};

  const unsigned short* Ab = A + row0*128;
  const unsigned short* Bb = Bt + (long)col0*128;
  int srow = lane >> 2;
  int soff = (lane & 3) * 8;
  int wrow = (wid>>1)*64, wcol = (wid&1)*64;

  for (int k0 = 0; k0 < 128; k0 += 32) {
    #pragma unroll
    for (int i=0;i<2;i++){
      int r = wid*32 + i*16;
      GL16(Ab + (long)(r + srow)*128 + k0 + soff, &As[r*32]);
      GL16(Bb + (long)(r + srow)*128 + k0 + soff, &Bs[r*32]);
    }
    __syncthreads();
    bf16x8 af[4], bfr[4];
    #pragma unroll
    for (int mi=0;mi<4;mi++)
      af[mi] = *(const bf16x8*)&As[(wrow + mi*16 + (lane&15))*32 + (lane>>4)*8];
    #pragma unroll
    for (int ni=0;ni<4;ni++)
      bfr[ni] = *(const bf16x8*)&Bs[(wcol + ni*16 + (lane&15))*32 + (lane>>4)*8];
    #pragma unroll
    for (int mi=0;mi<4;mi++)
      #pragma unroll
      for (int ni=0;ni<4;ni++)
        acc[mi][ni] = __builtin_amdgcn_mfma_f32_16x16x32_bf16(af[mi], bfr[ni], acc[mi][ni], 0,0,0);
    __syncthreads();
  }

  #pragma unroll
  for (int mi=0;mi<4;mi++){
    #pragma unroll
    for (int ni=0;ni<4;ni++){
      int col = col0 + wcol + ni*16 + (lane&15);
      float bsv = bias[col];
      #pragma unroll
      for (int r=0;r<4;r++){
        long grow = row0 + wrow + mi*16 + (lane>>4)*4 + r;
        C[grow*OUT_ + col] = acc[mi][ni][r] + bsv;
      }
    }
  }
}

extern "C" void kernel_launch(void* const* d_in, const int* in_sizes, int n_in,
                              void* d_out, int out_size, void* d_ws, size_t ws_size,
                              hipStream_t stream) {
  const float* hidden = (const float*)d_in[0];   // (B,T,H)
  const float* Wp     = (const float*)d_in[1];   // (1024,512)
  const float* bp     = (const float*)d_in[2];   // (512)
  const float* Wo     = (const float*)d_in[3];   // (128,1024)
  const float* bo     = (const float*)d_in[4];   // (1024)
  float* out    = (float*)d_out;                 // (B,T,1024) then final_state (B,128,128)
  float* fstate = out + (long)M_ * OUT_;

  char* w = (char*)d_ws;
  // region A [0,64MB): hbf (live: convH..proj), then opart bf16 (live: scan..reduce8)
  unsigned short* hbf   = (unsigned short*)w;
  unsigned short* opart = (unsigned short*)w;
  // region B [64MB,104MB): qbf/kbf/vbf (8MB each) + gf f32 (16MB); obf reuses qbf after scan
  unsigned short* qbf = (unsigned short*)(w + 67108864);
  unsigned short* kbf = qbf + (long)M_*K_;
  unsigned short* vbf = kbf + (long)M_*K_;
  float*          gf  = (float*)(vbf + (long)M_*K_);
  unsigned short* obf = qbf;
  // region C [104MB,105.25MB): transposed bf16 weights
  unsigned short* Wpt = (unsigned short*)(w + 67108864 + 41943040);
  unsigned short* Wot = Wpt + 512*1024;

  convH<<<16384, 256, 0, stream>>>(hidden, hbf);
  convW<<<2560, 256, 0, stream>>>(Wp, Wo, Wpt, Wot);
  proj_mfma<<<dim3(4, 256), 256, 0, stream>>>(hbf, Wpt, bp, qbf, kbf, gf, vbf);
  scan3<<<dim3(8, 8, 8), 64, 0, stream>>>(qbf, kbf, vbf, gf, opart, fstate);
  reduce8<<<2048, 256, 0, stream>>>(opart, obf);
  out_mfma<<<dim3(8, 256), 256, 0, stream>>>(obf, Wot, bo, out);
}

// Round 4
// 211.796 us; speedup vs baseline: 21.5163x; 2.0863x over previous
//
#include <hip/hip_runtime.h>
#include <math.h>

#define B_ 8
#define T_ 4096
#define H_ 1024
#define K_ 128
#define V_ 128
#define OUT_ 1024
#define NPROJ 512
#define M_ (B_*T_)          // 32768
#define CC 32               // chunk length
#define NC 128              // chunks per batch

typedef __attribute__((ext_vector_type(8))) short bf16x8;
typedef __attribute__((ext_vector_type(4))) float f32x4;

__device__ inline unsigned short f2bf(float f){
  union{float f; unsigned int u;} x; x.f = f;
  unsigned int r = x.u + 0x7fff + ((x.u>>16)&1);   // RNE
  return (unsigned short)(r>>16);
}
__device__ inline float bf2f(unsigned short u){
  union{unsigned int i; float f;} x; x.i = ((unsigned int)u)<<16; return x.f;
}

#define GL16(gp, lp) __builtin_amdgcn_global_load_lds(\
  (const __attribute__((address_space(1))) unsigned int*)(gp), \
  (__attribute__((address_space(3))) unsigned int*)(lp), 16, 0, 0)

#define MFMA16(a,b,c) __builtin_amdgcn_mfma_f32_16x16x32_bf16((a),(b),(c),0,0,0)

// ---------------- convert hidden f32 -> bf16
__global__ __launch_bounds__(256)
void convH(const float* __restrict__ x, unsigned short* __restrict__ y) {
  long i = (long)blockIdx.x*256 + threadIdx.x;
  float4 a = *(const float4*)(x + i*8);
  float4 b = *(const float4*)(x + i*8 + 4);
  unsigned short o[8] = {f2bf(a.x),f2bf(a.y),f2bf(a.z),f2bf(a.w),
                         f2bf(b.x),f2bf(b.y),f2bf(b.z),f2bf(b.w)};
  *(uint4*)(y + i*8) = *(uint4*)o;
}

// ---------------- transpose+convert weights
__global__ __launch_bounds__(256)
void convW(const float* __restrict__ Wp, const float* __restrict__ Wo,
           unsigned short* __restrict__ Wpt, unsigned short* __restrict__ Wot) {
  int i = blockIdx.x*256 + threadIdx.x;
  if (i < 512*1024) {
    int n = i >> 10, k = i & 1023;
    Wpt[i] = f2bf(Wp[(long)k*512 + n]);
  } else {
    int j = i - 512*1024;             // < 1024*128
    int o = j >> 7, v = j & 127;
    Wot[j] = f2bf(Wo[(long)v*1024 + o]);
  }
}

// ---------------- proj MFMA GEMM: [32768x1024]bf16 @ [1024x512] -> q/k/g/v arrays
__global__ __launch_bounds__(256)
void proj_mfma(const unsigned short* __restrict__ A, const unsigned short* __restrict__ Bt,
               const float* __restrict__ bias,
               unsigned short* __restrict__ qbf, unsigned short* __restrict__ kbf,
               float* __restrict__ gf, unsigned short* __restrict__ vbf) {
  __shared__ unsigned short As[128*32];
  __shared__ unsigned short Bs[128*32];
  int tid = threadIdx.x, lane = tid & 63, wid = tid >> 6;
  long row0 = (long)blockIdx.y * 128;
  int bx = blockIdx.x;
  int col0 = bx * 128;
  f32x4 acc[4][4];
  #pragma unroll
  for (int i=0;i<4;i++)
    #pragma unroll
    for (int j=0;j<4;j++) acc[i][j] = (f32x4){0.f,0.f,0.f,0.f};

  const unsigned short* Ab = A + row0*1024;
  const unsigned short* Bb = Bt + (long)col0*1024;
  int srow = lane >> 2;
  int soff = (lane & 3) * 8;
  int wrow = (wid>>1)*64, wcol = (wid&1)*64;

  for (int k0 = 0; k0 < 1024; k0 += 32) {
    #pragma unroll
    for (int i=0;i<2;i++){
      int r = wid*32 + i*16;
      GL16(Ab + (long)(r + srow)*1024 + k0 + soff, &As[r*32]);
      GL16(Bb + (long)(r + srow)*1024 + k0 + soff, &Bs[r*32]);
    }
    __syncthreads();
    bf16x8 af[4], bfr[4];
    #pragma unroll
    for (int mi=0;mi<4;mi++)
      af[mi] = *(const bf16x8*)&As[(wrow + mi*16 + (lane&15))*32 + (lane>>4)*8];
    #pragma unroll
    for (int ni=0;ni<4;ni++)
      bfr[ni] = *(const bf16x8*)&Bs[(wcol + ni*16 + (lane&15))*32 + (lane>>4)*8];
    #pragma unroll
    for (int mi=0;mi<4;mi++)
      #pragma unroll
      for (int ni=0;ni<4;ni++)
        acc[mi][ni] = MFMA16(af[mi], bfr[ni], acc[mi][ni]);
    __syncthreads();
  }

  #pragma unroll
  for (int mi=0;mi<4;mi++){
    #pragma unroll
    for (int ni=0;ni<4;ni++){
      int cloc = wcol + ni*16 + (lane&15);
      float bsv = bias[col0 + cloc];
      #pragma unroll
      for (int r=0;r<4;r++){
        long grow = row0 + wrow + mi*16 + (lane>>4)*4 + r;
        float v = acc[mi][ni][r] + bsv;
        long off = grow*128 + cloc;
        if (bx == 0)      qbf[off] = f2bf(v);
        else if (bx == 1) kbf[off] = f2bf(1.f/(1.f+__expf(-v)));
        else if (bx == 2) gf[off]  = 1.f/(1.f+__expf(-v));
        else              vbf[off] = f2bf(v);
      }
    }
  }
}

// ---------------- prep: per (b,c): G cumprod, q~ (in-place), k~ (in-place), k^T, vT, Gc
__global__ __launch_bounds__(128)
void prep(const float* __restrict__ gf, unsigned short* __restrict__ qbf,
          unsigned short* __restrict__ kbf, const unsigned short* __restrict__ vbf,
          unsigned short* __restrict__ khT, unsigned short* __restrict__ vT,
          float* __restrict__ Gc) {
  int k = threadIdx.x;               // 0..127
  int c = blockIdx.x, b = blockIdx.y;
  long base = ((long)b*T_ + (long)c*CC) * 128;
  float G = 1.f;
  float kt[CC];
  unsigned short vv[CC];
  #pragma unroll
  for (int t=0;t<CC;++t){
    long off = base + (long)t*128 + k;
    float g = gf[off];
    G *= g;
    float q = bf2f(qbf[off]);
    qbf[off] = f2bf(q*G);
    float kk = bf2f(kbf[off]);
    float ktl = kk/G;
    kbf[off] = f2bf(ktl);
    kt[t] = ktl;
    vv[t] = vbf[off];                // lane index doubles as v index
  }
  long cb = (long)b*NC + c;
  Gc[cb*128 + k] = G;
  unsigned short ob[CC];
  #pragma unroll
  for (int s=0;s<CC;++s) ob[s] = f2bf(kt[s]*G);
  long tbase = (cb*128 + k)*CC;
  #pragma unroll
  for (int j=0;j<4;j++) *(uint4*)(khT + tbase + j*8) = *(uint4*)(ob + j*8);
  #pragma unroll
  for (int j=0;j<4;j++) *(uint4*)(vT + tbase + j*8) = *(uint4*)(vv + j*8);
}

// ---------------- chunkstate: Ut[c][v][k] = sum_s V[s][v] * k^[s][k]  (bf16 out)
__global__ __launch_bounds__(256)
void chunkstate(const unsigned short* __restrict__ khT, const unsigned short* __restrict__ vT,
                unsigned short* __restrict__ Ut) {
  __shared__ unsigned short kS[128][36];
  __shared__ unsigned short vS[128][36];
  int tid = threadIdx.x, lane = tid&63, w = tid>>6;
  long cb = (long)blockIdx.y*NC + blockIdx.x;
  const unsigned short* kg = khT + cb*4096;
  const unsigned short* vg = vT  + cb*4096;
  #pragma unroll
  for (int j=0;j<2;j++){
    int idx = tid + j*256;           // 512 x uint4
    int r = idx>>2, s8 = (idx&3)*8;
    *(uint4*)&kS[r][s8] = *(const uint4*)(kg + r*32 + s8);
    *(uint4*)&vS[r][s8] = *(const uint4*)(vg + r*32 + s8);
  }
  __syncthreads();
  int l16 = lane&15, g8 = (lane>>4)*8;
  bf16x8 af[2], bfr[8];
  #pragma unroll
  for (int i=0;i<2;i++) af[i] = *(const bf16x8*)&vS[w*32 + i*16 + l16][g8];
  #pragma unroll
  for (int j=0;j<8;j++) bfr[j] = *(const bf16x8*)&kS[j*16 + l16][g8];
  #pragma unroll
  for (int i=0;i<2;i++){
    #pragma unroll
    for (int j=0;j<8;j++){
      f32x4 acc = (f32x4){0.f,0.f,0.f,0.f};
      acc = MFMA16(af[i], bfr[j], acc);
      int kcol = j*16 + l16;
      #pragma unroll
      for (int r=0;r<4;r++){
        int vrow = w*32 + i*16 + (lane>>4)*4 + r;
        Ut[cb*16384 + vrow*128 + kcol] = f2bf(acc[r]);
      }
    }
  }
}

// ---------------- seqstate: chunk-state recurrence; cellT written in-place over Ut
__global__ __launch_bounds__(256)
void seqstate(const float* __restrict__ Gc, unsigned short* __restrict__ Ut,
              float* __restrict__ fstate) {
  int idx = blockIdx.x*256 + threadIdx.x;    // 0..4095
  int b = blockIdx.y;
  int v = idx>>5, k0 = (idx&31)*4;
  float cell[4] = {0.f,0.f,0.f,0.f};
  long ub = (long)b*NC*16384 + (long)v*128 + k0;
  long gb = (long)b*NC*128 + k0;
  #pragma unroll 2
  for (int c=0; c<NC; ++c){
    uint2 u = *(const uint2*)(Ut + ub + (long)c*16384);
    float4 gc = *(const float4*)(Gc + gb + (long)c*128);
    unsigned short cb4[4] = {f2bf(cell[0]), f2bf(cell[1]), f2bf(cell[2]), f2bf(cell[3])};
    *(uint2*)(Ut + ub + (long)c*16384) = *(uint2*)cb4;   // cellT[c] (pre-update)
    cell[0] = fmaf(cell[0], gc.x, bf2f((unsigned short)(u.x & 0xffff)));
    cell[1] = fmaf(cell[1], gc.y, bf2f((unsigned short)(u.x >> 16)));
    cell[2] = fmaf(cell[2], gc.z, bf2f((unsigned short)(u.y & 0xffff)));
    cell[3] = fmaf(cell[3], gc.w, bf2f((unsigned short)(u.y >> 16)));
  }
  #pragma unroll
  for (int j=0;j<4;j++)
    fstate[((long)b*128 + k0 + j)*128 + v] = cell[j];
}

// ---------------- chunkout: O = tril(Q~ K~^T) @ V + Q~ @ cellT^T  -> obf bf16
#define CP 140
__global__ __launch_bounds__(256)
void chunkout(const unsigned short* __restrict__ qbf, const unsigned short* __restrict__ kbf,
              const unsigned short* __restrict__ vT, const unsigned short* __restrict__ cellT,
              unsigned short* __restrict__ obf) {
  __shared__ unsigned short qS[32][CP];
  __shared__ unsigned short kS[32][CP];
  __shared__ unsigned short cS[128][CP];
  __shared__ unsigned short vS[128][36];
  __shared__ unsigned short pS[4][32][36];
  int tid = threadIdx.x, lane = tid&63, w = tid>>6;
  long cb = (long)blockIdx.y*NC + blockIdx.x;
  const unsigned short* qg = qbf + cb*4096;
  const unsigned short* kg = kbf + cb*4096;
  const unsigned short* vg = vT  + cb*4096;
  const unsigned short* cg = cellT + cb*16384;
  // stage q,k (32x128), v (128x32), cell (128x128)
  #pragma unroll
  for (int j=0;j<2;j++){
    int idx = tid + j*256;           // 512
    int r = idx>>4, c8 = (idx&15)*8;
    *(uint4*)&qS[r][c8] = *(const uint4*)(qg + r*128 + c8);
    *(uint4*)&kS[r][c8] = *(const uint4*)(kg + r*128 + c8);
    int rv = idx>>2, s8 = (idx&3)*8;
    *(uint4*)&vS[rv][s8] = *(const uint4*)(vg + rv*32 + s8);
  }
  #pragma unroll
  for (int j=0;j<8;j++){
    int idx = tid + j*256;           // 2048
    int r = idx>>4, c8 = (idx&15)*8;
    *(uint4*)&cS[r][c8] = *(const uint4*)(cg + r*128 + c8);
  }
  __syncthreads();

  int l16 = lane&15, g = lane>>4, g8 = g*8;
  // S tiles: S2[s][t], compute (s0,t0),(s0,t1),(s1,t1)
  f32x4 s00 = (f32x4){0.f,0.f,0.f,0.f}, s01 = s00, s11 = s00;
  #pragma unroll
  for (int ks=0; ks<4; ++ks){
    bf16x8 ka = *(const bf16x8*)&kS[l16][ks*32+g8];
    bf16x8 kb = *(const bf16x8*)&kS[16+l16][ks*32+g8];
    bf16x8 qa = *(const bf16x8*)&qS[l16][ks*32+g8];
    bf16x8 qb = *(const bf16x8*)&qS[16+l16][ks*32+g8];
    s00 = MFMA16(ka, qa, s00);
    s01 = MFMA16(ka, qb, s01);
    s11 = MFMA16(kb, qb, s11);
  }
  // P[t][s] = masked S2, bf16. zero quadrant t<16, s>=16
  pS[w][l16][16 + 4*g + (0)] = 0; pS[w][l16][16 + 4*g + 1] = 0;
  pS[w][l16][16 + 4*g + 2] = 0;   pS[w][l16][16 + 4*g + 3] = 0;
  #pragma unroll
  for (int r=0;r<4;r++){
    int sl = 4*g + r;
    pS[w][l16][sl]       = (l16 >= sl) ? f2bf(s00[r]) : (unsigned short)0;
    pS[w][16+l16][sl]    = f2bf(s01[r]);
    pS[w][16+l16][16+sl] = (l16 >= sl) ? f2bf(s11[r]) : (unsigned short)0;
  }
  // O = P@V + Q~@cellT
  f32x4 o[2][2];
  #pragma unroll
  for (int i=0;i<2;i++)
    #pragma unroll
    for (int j=0;j<2;j++) o[i][j] = (f32x4){0.f,0.f,0.f,0.f};
  {
    bf16x8 p0 = *(const bf16x8*)&pS[w][l16][g8];
    bf16x8 p1 = *(const bf16x8*)&pS[w][16+l16][g8];
    bf16x8 v0 = *(const bf16x8*)&vS[w*32 + l16][g8];
    bf16x8 v1 = *(const bf16x8*)&vS[w*32 + 16 + l16][g8];
    o[0][0] = MFMA16(p0, v0, o[0][0]);
    o[0][1] = MFMA16(p0, v1, o[0][1]);
    o[1][0] = MFMA16(p1, v0, o[1][0]);
    o[1][1] = MFMA16(p1, v1, o[1][1]);
  }
  #pragma unroll
  for (int ks=0; ks<4; ++ks){
    bf16x8 qa = *(const bf16x8*)&qS[l16][ks*32+g8];
    bf16x8 qb = *(const bf16x8*)&qS[16+l16][ks*32+g8];
    bf16x8 c0 = *(const bf16x8*)&cS[w*32 + l16][ks*32+g8];
    bf16x8 c1 = *(const bf16x8*)&cS[w*32 + 16 + l16][ks*32+g8];
    o[0][0] = MFMA16(qa, c0, o[0][0]);
    o[0][1] = MFMA16(qa, c1, o[0][1]);
    o[1][0] = MFMA16(qb, c0, o[1][0]);
    o[1][1] = MFMA16(qb, c1, o[1][1]);
  }
  // store obf[t][v]
  #pragma unroll
  for (int ti=0;ti<2;ti++)
    #pragma unroll
    for (int vi=0;vi<2;vi++)
      #pragma unroll
      for (int r=0;r<4;r++){
        int t = ti*16 + 4*g + r;
        int v = w*32 + vi*16 + l16;
        obf[cb*4096 + (long)t*128 + v] = f2bf(o[ti][vi][r]);
      }
}

// ---------------- out MFMA GEMM: [32768x128]bf16 @ [128x1024] + bias -> f32
__global__ __launch_bounds__(256)
void out_mfma(const unsigned short* __restrict__ A, const unsigned short* __restrict__ Bt,
              const float* __restrict__ bias, float* __restrict__ C) {
  __shared__ unsigned short As[128*32];
  __shared__ unsigned short Bs[128*32];
  int tid = threadIdx.x, lane = tid & 63, wid = tid >> 6;
  long row0 = (long)blockIdx.y * 128;
  int col0 = blockIdx.x * 128;
  f32x4 acc[4][4];
  #pragma unroll
  for (int i=0;i<4;i++)
    #pragma unroll
    for (int j=0;j<4;j++) acc[i][j] = (f32x4){0.f,0.f,0.f,0.f};

  const unsigned short* Ab = A + row0*128;
  const unsigned short* Bb = Bt + (long)col0*128;
  int srow = lane >> 2;
  int soff = (lane & 3) * 8;
  int wrow = (wid>>1)*64, wcol = (wid&1)*64;

  for (int k0 = 0; k0 < 128; k0 += 32) {
    #pragma unroll
    for (int i=0;i<2;i++){
      int r = wid*32 + i*16;
      GL16(Ab + (long)(r + srow)*128 + k0 + soff, &As[r*32]);
      GL16(Bb + (long)(r + srow)*128 + k0 + soff, &Bs[r*32]);
    }
    __syncthreads();
    bf16x8 af[4], bfr[4];
    #pragma unroll
    for (int mi=0;mi<4;mi++)
      af[mi] = *(const bf16x8*)&As[(wrow + mi*16 + (lane&15))*32 + (lane>>4)*8];
    #pragma unroll
    for (int ni=0;ni<4;ni++)
      bfr[ni] = *(const bf16x8*)&Bs[(wcol + ni*16 + (lane&15))*32 + (lane>>4)*8];
    #pragma unroll
    for (int mi=0;mi<4;mi++)
      #pragma unroll
      for (int ni=0;ni<4;ni++)
        acc[mi][ni] = MFMA16(af[mi], bfr[ni], acc[mi][ni]);
    __syncthreads();
  }

  #pragma unroll
  for (int mi=0;mi<4;mi++){
    #pragma unroll
    for (int ni=0;ni<4;ni++){
      int col = col0 + wcol + ni*16 + (lane&15);
      float bsv = bias[col];
      #pragma unroll
      for (int r=0;r<4;r++){
        long grow = row0 + wrow + mi*16 + (lane>>4)*4 + r;
        C[grow*OUT_ + col] = acc[mi][ni][r] + bsv;
      }
    }
  }
}

extern "C" void kernel_launch(void* const* d_in, const int* in_sizes, int n_in,
                              void* d_out, int out_size, void* d_ws, size_t ws_size,
                              hipStream_t stream) {
  const float* hidden = (const float*)d_in[0];
  const float* Wp     = (const float*)d_in[1];
  const float* bp     = (const float*)d_in[2];
  const float* Wo     = (const float*)d_in[3];
  const float* bo     = (const float*)d_in[4];
  float* out    = (float*)d_out;
  float* fstate = out + (long)M_ * OUT_;

  char* w = (char*)d_ws;
  // overlay region [0,64MB): hbf (convH..proj) then scan intermediates
  unsigned short* hbf   = (unsigned short*)w;
  unsigned short* khT   = (unsigned short*)w;                     // 8 MB
  unsigned short* vT    = (unsigned short*)(w + 8388608);         // 8 MB
  float*          Gc    = (float*)(w + 16777216);                 // 0.5 MB
  unsigned short* Ut    = (unsigned short*)(w + 17301504);        // 32 MB (also cellT)
  unsigned short* obf   = (unsigned short*)(w + 50855936);        // 8 MB
  // persistent region
  unsigned short* Wot = (unsigned short*)(w + 67108864);          // 0.25 MB
  unsigned short* Wpt = (unsigned short*)(w + 67371008);          // 1 MB
  unsigned short* qbf = (unsigned short*)(w + 68419584);          // 8 MB
  unsigned short* kbf = (unsigned short*)(w + 76808192);          // 8 MB
  unsigned short* vbf = (unsigned short*)(w + 85196800);          // 8 MB
  float*          gf  = (float*)(w + 93585408);                   // 16 MB

  convH<<<16384, 256, 0, stream>>>(hidden, hbf);
  convW<<<2560, 256, 0, stream>>>(Wp, Wo, Wpt, Wot);
  proj_mfma<<<dim3(4, 256), 256, 0, stream>>>(hbf, Wpt, bp, qbf, kbf, gf, vbf);
  prep<<<dim3(NC, B_), 128, 0, stream>>>(gf, qbf, kbf, vbf, khT, vT, Gc);
  chunkstate<<<dim3(NC, B_), 256, 0, stream>>>(khT, vT, Ut);
  seqstate<<<dim3(16, B_), 256, 0, stream>>>(Gc, Ut, fstate);
  chunkout<<<dim3(NC, B_), 256, 0, stream>>>(qbf, kbf, vT, Ut, obf);
  out_mfma<<<dim3(8, 256), 256, 0, stream>>>(obf, Wot, bo, out);
}

// Round 5
// 192.903 us; speedup vs baseline: 23.6237x; 1.0979x over previous
//
#include <hip/hip_runtime.h>
#include <math.h>

#define B_ 8
#define T_ 4096
#define H_ 1024
#define K_ 128
#define V_ 128
#define OUT_ 1024
#define NPROJ 512
#define M_ (B_*T_)          // 32768
#define CC 32               // chunk length
#define NC 128              // chunks per batch

typedef __attribute__((ext_vector_type(8))) short bf16x8;
typedef __attribute__((ext_vector_type(4))) float f32x4;

__device__ inline unsigned short f2bf(float f){
  union{float f; unsigned int u;} x; x.f = f;
  unsigned int r = x.u + 0x7fff + ((x.u>>16)&1);   // RNE
  return (unsigned short)(r>>16);
}
__device__ inline float bf2f(unsigned short u){
  union{unsigned int i; float f;} x; x.i = ((unsigned int)u)<<16; return x.f;
}

#define GL16(gp, lp) __builtin_amdgcn_global_load_lds(\
  (const __attribute__((address_space(1))) unsigned int*)(gp), \
  (__attribute__((address_space(3))) unsigned int*)(lp), 16, 0, 0)

#define MFMA16(a,b,c) __builtin_amdgcn_mfma_f32_16x16x32_bf16((a),(b),(c),0,0,0)

// ---------------- generic tiled transpose+convert: dst[n][k] = bf16(src[k][n])
// grid (N/32, Kd/32), 256 threads
__global__ __launch_bounds__(256)
void convT(const float* __restrict__ src, unsigned short* __restrict__ dst,
           int Kd, int N) {
  __shared__ float t[32][33];
  int tx = threadIdx.x & 31, ty = threadIdx.x >> 5;   // ty 0..7
  int n0 = blockIdx.x * 32, k0 = blockIdx.y * 32;
  #pragma unroll
  for (int r=0;r<4;r++){
    int k = ty*4 + r;
    t[k][tx] = src[(long)(k0+k)*N + n0 + tx];
  }
  __syncthreads();
  #pragma unroll
  for (int r=0;r<4;r++){
    int n = ty*4 + r;
    dst[(long)(n0+n)*Kd + k0 + tx] = f2bf(t[tx][n]);
  }
}

// ---------------- proj MFMA GEMM v2: [32768x1024]f32(A, inline bf16 cvt) @ [1024x512]
// BM=128, BN=512, BK=32, 512 thr (8 waves, 2M x 4N), grid 256. Double-buffered LDS.
__global__ __launch_bounds__(512)
void proj_mfma2(const float* __restrict__ A, const unsigned short* __restrict__ Bt,
                const float* __restrict__ bias,
                unsigned short* __restrict__ qbf, unsigned short* __restrict__ kbf,
                float* __restrict__ gf, unsigned short* __restrict__ vbf) {
  __shared__ unsigned short sA[2][128*32];
  __shared__ unsigned short sB[2][512*32];
  int tid = threadIdx.x, lane = tid & 63, wid = tid >> 6;
  int wm = wid >> 2, wn = wid & 3;
  int l16 = lane & 15, g8 = (lane >> 4) * 8;
  long row0 = (long)blockIdx.x * 128;

  // A staging: thread -> (arow 0..127, akoff 0/8/16/24)
  int arow = tid >> 2, akoff = (tid & 3) * 8;
  const float* Ab = A + (row0 + arow) * 1024 + akoff;
  // B staging (GL16): per wave rows wid*64..+63
  int srow = lane >> 2, soff = (lane & 3) * 8;

  f32x4 acc[4][8];
  #pragma unroll
  for (int i=0;i<4;i++)
    #pragma unroll
    for (int j=0;j<8;j++) acc[i][j] = (f32x4){0.f,0.f,0.f,0.f};

  float4 ra0, ra1;
  #define LDA(k0_) { ra0 = *(const float4*)(Ab + (k0_)); ra1 = *(const float4*)(Ab + (k0_) + 4); }
  #define STB(b_, k0_) { _Pragma("unroll") \
    for (int i_=0;i_<4;i_++){ \
      int n0_ = wid*64 + i_*16; \
      GL16(Bt + (long)(n0_ + srow)*1024 + (k0_) + soff, &sB[b_][n0_*32]); \
    } }
  #define STA(b_) { \
    unsigned short o_[8] = {f2bf(ra0.x),f2bf(ra0.y),f2bf(ra0.z),f2bf(ra0.w), \
                            f2bf(ra1.x),f2bf(ra1.y),f2bf(ra1.z),f2bf(ra1.w)}; \
    *(uint4*)&sA[b_][arow*32 + akoff] = *(uint4*)o_; \
  }

  LDA(0);
  STB(0, 0);
  STA(0);
  __syncthreads();

  int cur = 0;
  for (int t = 0; t < 32; ++t) {
    int k0n = (t+1) * 32;
    if (t < 31) { LDA(k0n); STB(cur^1, k0n); }
    bf16x8 af[4], bf[8];
    #pragma unroll
    for (int mi=0;mi<4;mi++)
      af[mi] = *(const bf16x8*)&sA[cur][(wm*64 + mi*16 + l16)*32 + g8];
    #pragma unroll
    for (int ni=0;ni<8;ni++)
      bf[ni] = *(const bf16x8*)&sB[cur][(wn*128 + ni*16 + l16)*32 + g8];
    #pragma unroll
    for (int mi=0;mi<4;mi++)
      #pragma unroll
      for (int ni=0;ni<8;ni++)
        acc[mi][ni] = MFMA16(af[mi], bf[ni], acc[mi][ni]);
    if (t < 31) { STA(cur^1); }
    __syncthreads();
    cur ^= 1;
  }
  #undef LDA
  #undef STB
  #undef STA

  // epilogue: wave wn owns output slab wn*128..+127 -> q/k/g/v
  #pragma unroll
  for (int mi=0;mi<4;mi++){
    #pragma unroll
    for (int ni=0;ni<8;ni++){
      int c = ni*16 + l16;                 // 0..127 within slab
      float bsv = bias[wn*128 + c];
      #pragma unroll
      for (int r=0;r<4;r++){
        long grow = row0 + wm*64 + mi*16 + (lane>>4)*4 + r;
        float v = acc[mi][ni][r] + bsv;
        long off = grow*128 + c;
        if (wn == 0)      qbf[off] = f2bf(v);
        else if (wn == 1) kbf[off] = f2bf(1.f/(1.f+__expf(-v)));
        else if (wn == 2) gf[off]  = 1.f/(1.f+__expf(-v));
        else              vbf[off] = f2bf(v);
      }
    }
  }
}

// ---------------- prep: per (b,c): G cumprod, q~ (in-place), k~ (in-place), k^T, vT, Gc
__global__ __launch_bounds__(128)
void prep(const float* __restrict__ gf, unsigned short* __restrict__ qbf,
          unsigned short* __restrict__ kbf, const unsigned short* __restrict__ vbf,
          unsigned short* __restrict__ khT, unsigned short* __restrict__ vT,
          float* __restrict__ Gc) {
  int k = threadIdx.x;               // 0..127
  int c = blockIdx.x, b = blockIdx.y;
  long base = ((long)b*T_ + (long)c*CC) * 128;
  float G = 1.f;
  float kt[CC];
  unsigned short vv[CC];
  #pragma unroll
  for (int t=0;t<CC;++t){
    long off = base + (long)t*128 + k;
    float g = gf[off];
    G *= g;
    float q = bf2f(qbf[off]);
    qbf[off] = f2bf(q*G);
    float kk = bf2f(kbf[off]);
    float ktl = kk/G;
    kbf[off] = f2bf(ktl);
    kt[t] = ktl;
    vv[t] = vbf[off];                // lane index doubles as v index
  }
  long cb = (long)b*NC + c;
  Gc[cb*128 + k] = G;
  unsigned short ob[CC];
  #pragma unroll
  for (int s=0;s<CC;++s) ob[s] = f2bf(kt[s]*G);
  long tbase = (cb*128 + k)*CC;
  #pragma unroll
  for (int j=0;j<4;j++) *(uint4*)(khT + tbase + j*8) = *(uint4*)(ob + j*8);
  #pragma unroll
  for (int j=0;j<4;j++) *(uint4*)(vT + tbase + j*8) = *(uint4*)(vv + j*8);
}

// ---------------- chunkstate: Ut[c][v][k] = sum_s V[s][v] * k^[s][k]  (bf16 out)
__global__ __launch_bounds__(256)
void chunkstate(const unsigned short* __restrict__ khT, const unsigned short* __restrict__ vT,
                unsigned short* __restrict__ Ut) {
  __shared__ unsigned short kS[128][36];
  __shared__ unsigned short vS[128][36];
  int tid = threadIdx.x, lane = tid&63, w = tid>>6;
  long cb = (long)blockIdx.y*NC + blockIdx.x;
  const unsigned short* kg = khT + cb*4096;
  const unsigned short* vg = vT  + cb*4096;
  #pragma unroll
  for (int j=0;j<2;j++){
    int idx = tid + j*256;           // 512 x uint4
    int r = idx>>2, s8 = (idx&3)*8;
    *(uint4*)&kS[r][s8] = *(const uint4*)(kg + r*32 + s8);
    *(uint4*)&vS[r][s8] = *(const uint4*)(vg + r*32 + s8);
  }
  __syncthreads();
  int l16 = lane&15, g8 = (lane>>4)*8;
  bf16x8 af[2], bfr[8];
  #pragma unroll
  for (int i=0;i<2;i++) af[i] = *(const bf16x8*)&vS[w*32 + i*16 + l16][g8];
  #pragma unroll
  for (int j=0;j<8;j++) bfr[j] = *(const bf16x8*)&kS[j*16 + l16][g8];
  #pragma unroll
  for (int i=0;i<2;i++){
    #pragma unroll
    for (int j=0;j<8;j++){
      f32x4 acc = (f32x4){0.f,0.f,0.f,0.f};
      acc = MFMA16(af[i], bfr[j], acc);
      int kcol = j*16 + l16;
      #pragma unroll
      for (int r=0;r<4;r++){
        int vrow = w*32 + i*16 + (lane>>4)*4 + r;
        Ut[cb*16384 + vrow*128 + kcol] = f2bf(acc[r]);
      }
    }
  }
}

// ---------------- seqstate: chunk-state recurrence; cellT written in-place over Ut
__global__ __launch_bounds__(256)
void seqstate(const float* __restrict__ Gc, unsigned short* __restrict__ Ut,
              float* __restrict__ fstate) {
  int idx = blockIdx.x*256 + threadIdx.x;    // 0..4095
  int b = blockIdx.y;
  int v = idx>>5, k0 = (idx&31)*4;
  float cell[4] = {0.f,0.f,0.f,0.f};
  long ub = (long)b*NC*16384 + (long)v*128 + k0;
  long gb = (long)b*NC*128 + k0;
  #pragma unroll 2
  for (int c=0; c<NC; ++c){
    uint2 u = *(const uint2*)(Ut + ub + (long)c*16384);
    float4 gc = *(const float4*)(Gc + gb + (long)c*128);
    unsigned short cb4[4] = {f2bf(cell[0]), f2bf(cell[1]), f2bf(cell[2]), f2bf(cell[3])};
    *(uint2*)(Ut + ub + (long)c*16384) = *(uint2*)cb4;   // cellT[c] (pre-update)
    cell[0] = fmaf(cell[0], gc.x, bf2f((unsigned short)(u.x & 0xffff)));
    cell[1] = fmaf(cell[1], gc.y, bf2f((unsigned short)(u.x >> 16)));
    cell[2] = fmaf(cell[2], gc.z, bf2f((unsigned short)(u.y & 0xffff)));
    cell[3] = fmaf(cell[3], gc.w, bf2f((unsigned short)(u.y >> 16)));
  }
  #pragma unroll
  for (int j=0;j<4;j++)
    fstate[((long)b*128 + k0 + j)*128 + v] = cell[j];
}

// ---------------- chunkout: O = tril(Q~ K~^T) @ V + Q~ @ cellT^T  -> obf bf16
#define CP 140
__global__ __launch_bounds__(256)
void chunkout(const unsigned short* __restrict__ qbf, const unsigned short* __restrict__ kbf,
              const unsigned short* __restrict__ vT, const unsigned short* __restrict__ cellT,
              unsigned short* __restrict__ obf) {
  __shared__ unsigned short qS[32][CP];
  __shared__ unsigned short kS[32][CP];
  __shared__ unsigned short cS[128][CP];
  __shared__ unsigned short vS[128][36];
  __shared__ unsigned short pS[4][32][36];
  int tid = threadIdx.x, lane = tid&63, w = tid>>6;
  long cb = (long)blockIdx.y*NC + blockIdx.x;
  const unsigned short* qg = qbf + cb*4096;
  const unsigned short* kg = kbf + cb*4096;
  const unsigned short* vg = vT  + cb*4096;
  const unsigned short* cg = cellT + cb*16384;
  // stage q,k (32x128), v (128x32), cell (128x128)
  #pragma unroll
  for (int j=0;j<2;j++){
    int idx = tid + j*256;           // 512
    int r = idx>>4, c8 = (idx&15)*8;
    *(uint4*)&qS[r][c8] = *(const uint4*)(qg + r*128 + c8);
    *(uint4*)&kS[r][c8] = *(const uint4*)(kg + r*128 + c8);
    int rv = idx>>2, s8 = (idx&3)*8;
    *(uint4*)&vS[rv][s8] = *(const uint4*)(vg + rv*32 + s8);
  }
  #pragma unroll
  for (int j=0;j<8;j++){
    int idx = tid + j*256;           // 2048
    int r = idx>>4, c8 = (idx&15)*8;
    *(uint4*)&cS[r][c8] = *(const uint4*)(cg + r*128 + c8);
  }
  __syncthreads();

  int l16 = lane&15, g = lane>>4, g8 = g*8;
  // S tiles: S2[s][t], compute (s0,t0),(s0,t1),(s1,t1)
  f32x4 s00 = (f32x4){0.f,0.f,0.f,0.f}, s01 = s00, s11 = s00;
  #pragma unroll
  for (int ks=0; ks<4; ++ks){
    bf16x8 ka = *(const bf16x8*)&kS[l16][ks*32+g8];
    bf16x8 kb = *(const bf16x8*)&kS[16+l16][ks*32+g8];
    bf16x8 qa = *(const bf16x8*)&qS[l16][ks*32+g8];
    bf16x8 qb = *(const bf16x8*)&qS[16+l16][ks*32+g8];
    s00 = MFMA16(ka, qa, s00);
    s01 = MFMA16(ka, qb, s01);
    s11 = MFMA16(kb, qb, s11);
  }
  // P[t][s] = masked S2, bf16. zero quadrant t<16, s>=16
  pS[w][l16][16 + 4*g + (0)] = 0; pS[w][l16][16 + 4*g + 1] = 0;
  pS[w][l16][16 + 4*g + 2] = 0;   pS[w][l16][16 + 4*g + 3] = 0;
  #pragma unroll
  for (int r=0;r<4;r++){
    int sl = 4*g + r;
    pS[w][l16][sl]       = (l16 >= sl) ? f2bf(s00[r]) : (unsigned short)0;
    pS[w][16+l16][sl]    = f2bf(s01[r]);
    pS[w][16+l16][16+sl] = (l16 >= sl) ? f2bf(s11[r]) : (unsigned short)0;
  }
  // O = P@V + Q~@cellT
  f32x4 o[2][2];
  #pragma unroll
  for (int i=0;i<2;i++)
    #pragma unroll
    for (int j=0;j<2;j++) o[i][j] = (f32x4){0.f,0.f,0.f,0.f};
  {
    bf16x8 p0 = *(const bf16x8*)&pS[w][l16][g8];
    bf16x8 p1 = *(const bf16x8*)&pS[w][16+l16][g8];
    bf16x8 v0 = *(const bf16x8*)&vS[w*32 + l16][g8];
    bf16x8 v1 = *(const bf16x8*)&vS[w*32 + 16 + l16][g8];
    o[0][0] = MFMA16(p0, v0, o[0][0]);
    o[0][1] = MFMA16(p0, v1, o[0][1]);
    o[1][0] = MFMA16(p1, v0, o[1][0]);
    o[1][1] = MFMA16(p1, v1, o[1][1]);
  }
  #pragma unroll
  for (int ks=0; ks<4; ++ks){
    bf16x8 qa = *(const bf16x8*)&qS[l16][ks*32+g8];
    bf16x8 qb = *(const bf16x8*)&qS[16+l16][ks*32+g8];
    bf16x8 c0 = *(const bf16x8*)&cS[w*32 + l16][ks*32+g8];
    bf16x8 c1 = *(const bf16x8*)&cS[w*32 + 16 + l16][ks*32+g8];
    o[0][0] = MFMA16(qa, c0, o[0][0]);
    o[0][1] = MFMA16(qa, c1, o[0][1]);
    o[1][0] = MFMA16(qb, c0, o[1][0]);
    o[1][1] = MFMA16(qb, c1, o[1][1]);
  }
  // store obf[t][v]
  #pragma unroll
  for (int ti=0;ti<2;ti++)
    #pragma unroll
    for (int vi=0;vi<2;vi++)
      #pragma unroll
      for (int r=0;r<4;r++){
        int t = ti*16 + 4*g + r;
        int v = w*32 + vi*16 + l16;
        obf[cb*4096 + (long)t*128 + v] = f2bf(o[ti][vi][r]);
      }
}

// ---------------- out MFMA GEMM: [32768x128]bf16 @ [128x1024] + bias -> f32
__global__ __launch_bounds__(256)
void out_mfma(const unsigned short* __restrict__ A, const unsigned short* __restrict__ Bt,
              const float* __restrict__ bias, float* __restrict__ C) {
  __shared__ unsigned short As[128*32];
  __shared__ unsigned short Bs[128*32];
  int tid = threadIdx.x, lane = tid & 63, wid = tid >> 6;
  long row0 = (long)blockIdx.y * 128;
  int col0 = blockIdx.x * 128;
  f32x4 acc[4][4];
  #pragma unroll
  for (int i=0;i<4;i++)
    #pragma unroll
    for (int j=0;j<4;j++) acc[i][j] = (f32x4){0.f,0.f,0.f,0.f};

  const unsigned short* Ab = A + row0*128;
  const unsigned short* Bb = Bt + (long)col0*128;
  int srow = lane >> 2;
  int soff = (lane & 3) * 8;
  int wrow = (wid>>1)*64, wcol = (wid&1)*64;

  for (int k0 = 0; k0 < 128; k0 += 32) {
    #pragma unroll
    for (int i=0;i<2;i++){
      int r = wid*32 + i*16;
      GL16(Ab + (long)(r + srow)*128 + k0 + soff, &As[r*32]);
      GL16(Bb + (long)(r + srow)*128 + k0 + soff, &Bs[r*32]);
    }
    __syncthreads();
    bf16x8 af[4], bfr[4];
    #pragma unroll
    for (int mi=0;mi<4;mi++)
      af[mi] = *(const bf16x8*)&As[(wrow + mi*16 + (lane&15))*32 + (lane>>4)*8];
    #pragma unroll
    for (int ni=0;ni<4;ni++)
      bfr[ni] = *(const bf16x8*)&Bs[(wcol + ni*16 + (lane&15))*32 + (lane>>4)*8];
    #pragma unroll
    for (int mi=0;mi<4;mi++)
      #pragma unroll
      for (int ni=0;ni<4;ni++)
        acc[mi][ni] = MFMA16(af[mi], bfr[ni], acc[mi][ni]);
    __syncthreads();
  }

  #pragma unroll
  for (int mi=0;mi<4;mi++){
    #pragma unroll
    for (int ni=0;ni<4;ni++){
      int col = col0 + wcol + ni*16 + (lane&15);
      float bsv = bias[col];
      #pragma unroll
      for (int r=0;r<4;r++){
        long grow = row0 + wrow + mi*16 + (lane>>4)*4 + r;
        C[grow*OUT_ + col] = acc[mi][ni][r] + bsv;
      }
    }
  }
}

extern "C" void kernel_launch(void* const* d_in, const int* in_sizes, int n_in,
                              void* d_out, int out_size, void* d_ws, size_t ws_size,
                              hipStream_t stream) {
  const float* hidden = (const float*)d_in[0];
  const float* Wp     = (const float*)d_in[1];
  const float* bp     = (const float*)d_in[2];
  const float* Wo     = (const float*)d_in[3];
  const float* bo     = (const float*)d_in[4];
  float* out    = (float*)d_out;
  float* fstate = out + (long)M_ * OUT_;

  char* w = (char*)d_ws;
  // overlay region [0,64MB): scan intermediates
  unsigned short* khT   = (unsigned short*)w;                     // 8 MB
  unsigned short* vT    = (unsigned short*)(w + 8388608);         // 8 MB
  float*          Gc    = (float*)(w + 16777216);                 // 0.5 MB
  unsigned short* Ut    = (unsigned short*)(w + 17301504);        // 32 MB (also cellT)
  unsigned short* obf   = (unsigned short*)(w + 50855936);        // 8 MB
  // persistent region
  unsigned short* Wot = (unsigned short*)(w + 67108864);          // 0.25 MB
  unsigned short* Wpt = (unsigned short*)(w + 67371008);          // 1 MB
  unsigned short* qbf = (unsigned short*)(w + 68419584);          // 8 MB
  unsigned short* kbf = (unsigned short*)(w + 76808192);          // 8 MB
  unsigned short* vbf = (unsigned short*)(w + 85196800);          // 8 MB
  float*          gf  = (float*)(w + 93585408);                   // 16 MB

  convT<<<dim3(NPROJ/32, H_/32), 256, 0, stream>>>(Wp, Wpt, H_, NPROJ);    // Wpt[512][1024]
  convT<<<dim3(OUT_/32, V_/32), 256, 0, stream>>>(Wo, Wot, V_, OUT_);      // Wot[1024][128]
  proj_mfma2<<<256, 512, 0, stream>>>(hidden, Wpt, bp, qbf, kbf, gf, vbf);
  prep<<<dim3(NC, B_), 128, 0, stream>>>(gf, qbf, kbf, vbf, khT, vT, Gc);
  chunkstate<<<dim3(NC, B_), 256, 0, stream>>>(khT, vT, Ut);
  seqstate<<<dim3(16, B_), 256, 0, stream>>>(Gc, Ut, fstate);
  chunkout<<<dim3(NC, B_), 256, 0, stream>>>(qbf, kbf, vT, Ut, obf);
  out_mfma<<<dim3(8, 256), 256, 0, stream>>>(obf, Wot, bo, out);
}